// Round 20
// baseline (93.981 us; speedup 1.0000x reference)
//
#include <hip/hip_runtime.h>
#include <stdint.h>

#define BB   16
#define NN   65536
#define FF   32
#define KSEL 16384
#define EPSF 1e-10f
#define GBIN 382u                // fallback 9-bit bucket logic (flagged path)
#define CAP_COL 11264            // candidates per column (fallback needs ~9.8K)
#define CAP_LDS 64               // LDS staged candidates per feature per block (λ≈22.5)
#define BLKB 128                 // kfused blocks per batch
#define CAP_U   2048             // unsure rows per batch (expected ~10)

typedef float f4v __attribute__((ext_vector_type(4)));

__device__ __forceinline__ uint32_t fkey(float s) {
    uint32_t u = __float_as_uint(s);
    return (u & 0x80000000u) ? ~u : (u | 0x80000000u);
}
// band bounds: float domain [0.64, 0.71) — equivalent to key domain (monotone)
#define BANDLO 0.64f
#define BANDHI 0.71f
#define KEYLO fkey(0.64f)
#define KEYHI fkey(0.71f)

// ---- workspace layout (uint32 element offsets), ~51 MB ----
#define WS_MIN    0                          // 1 word (memset 0xFF)
#define WS_REM    8                          // [512]
#define WS_T      1032                       // u64[512] (byte 4128, 8-aligned)
#define WS_EQC    2056                       // [512] cand counters   (memset 0 from here...)
#define WS_UCNT   2568                       // [16] unsure counters
#define WS_FLAG   2584                       // [16] guess-miss flags
#define WS_MNOT   2600                       // 1 word: nonzero if mask has a non-1.0 element
#define WS_PREF   2624                       // [512] bucket per column (...to here: 1080 words)
#define WS_PA     4096                       // [2048][32] per-block above-counts
#define WS_PI     69632                      // [2048][32] per-block in-counts
#define WS_NLIST  135168                     // [16][CAP_U] row indices
#define WS_ULIST  167936                     // [16][CAP_U][32] f32 rows
#define WS_CAND   1216512                    // u64[512][CAP_COL] (byte 4866048, 8-aligned)

// ---- 1) fused: min + mask-check + band counts (register) + cand collect + output mark ----
// A/B vs round 19: CACHED output stores (L3 absorbs the 138MB write stream) instead of NT.
__global__ __launch_bounds__(256, 4) void kfused(const float* __restrict__ xf,
                                                 const float* __restrict__ mask,
                                                 uint32_t* __restrict__ ws,
                                                 float* __restrict__ upd,
                                                 float* __restrict__ omask) {
    __shared__ uint64_t lbuf[32][CAP_LDS];
    __shared__ uint32_t lcnt[32], lbase[32], labove[32];
    __shared__ uint32_t rmin[4];
    const int b = blockIdx.x >> 7;
    const int blk = blockIdx.x & 127;
    const int tid = threadIdx.x;
    if (tid < 32) { lcnt[tid] = 0; labove[tid] = 0; }
    __syncthreads();
    if (tid < 128) {  // mask uniformity check: 128 float4 slice per block covers all of mask
        float4 a = ((const float4*)mask)[(size_t)blockIdx.x * 128 + tid];
        if ((a.x != 1.0f) | (a.y != 1.0f) | (a.z != 1.0f) | (a.w != 1.0f)) ws[WS_MNOT] = 1u;
    }
    const float4* x4 = (const float4*)xf + (size_t)b * 524288;
    f4v* o4 = (f4v*)omask + (size_t)b * 524288;
    const int lane = tid & 63;
    const int fb = (tid & 7) * 4;            // this thread ALWAYS serves features fb..fb+3
    uint64_t* gcand = (uint64_t*)(ws + WS_CAND);
    float* ulist = (float*)(ws + WS_ULIST);
    uint32_t mreg = 0xFFFFFFFFu;
    uint32_t acnt[4] = {0, 0, 0, 0};
    float4 v[16];
#pragma unroll
    for (int k = 0; k < 16; ++k) v[k] = x4[blk * 4096 + k * 256 + tid];
    __builtin_amdgcn_sched_barrier(0);
#pragma unroll
    for (int k = 0; k < 16; ++k) {
        const int e = blk * 4096 + k * 256 + tid;
        const int n = e >> 3;
        float vv[4] = {v[k].x, v[k].y, v[k].z, v[k].w};
        bool ab[4], ib[4];
#pragma unroll
        for (int j = 0; j < 4; ++j) {
            uint32_t u = __float_as_uint(vv[j]);
            uint32_t a = u & 0x7FFFFFFFu;
            mreg = a < mreg ? a : mreg;
            ab[j] = vv[j] >= BANDHI;
            ib[j] = (vv[j] >= BANDLO) & !ab[j];
            acnt[j] += ab[j] ? 1u : 0u;
            if (ib[j]) {                       // rare (2.2%): compute key only here
                const int f = fb + j;
                uint64_t v64 = ((uint64_t)fkey(vv[j]) << 32) | (uint32_t)n;
                uint32_t idx = atomicAdd(&lcnt[f], 1u);
                if (idx < CAP_LDS) {
                    lbuf[f][idx] = v64;
                } else {               // statistically never (22.5 avg vs 64 cap)
                    uint32_t col = (uint32_t)(b * 32 + f);
                    uint32_t pos = atomicAdd(&ws[WS_EQC + col], 1u);
                    if (pos < CAP_COL) gcand[(size_t)col * CAP_COL + pos] = v64;
                }
            }
        }
        bool sure = ab[0] | ab[1] | ab[2] | ab[3];
        bool bnd = ib[0] | ib[1] | ib[2] | ib[3];
        unsigned long long balS = __ballot(sure);
        unsigned long long balB = __ballot(bnd);
        uint32_t grpS = (uint32_t)(balS >> (lane & 56)) & 0xFFu;
        uint32_t grpB = (uint32_t)(balB >> (lane & 56)) & 0xFFu;
        if (grpS || !grpB) {                       // decided row (sure OR out): branchless store
            float u1 = grpS ? 1.0f : 0.0f;
            f4v o;
            o.x = vv[0] * u1; o.y = vv[1] * u1; o.z = vv[2] * u1; o.w = vv[3] * u1;
            o4[e] = o;                             // cached: L3 absorbs write stream
            if ((tid & 7) == 0) upd[(size_t)b * NN + n] = u1;
        } else {                                   // unsure: defer to kfix2 (~1e-4 of rows)
            uint32_t slot = 0xFFFFFFFFu;
            if ((tid & 7) == 0) slot = atomicAdd(&ws[WS_UCNT + b], 1u);
            slot = __shfl(slot, (lane & 56));
            if (slot < CAP_U) {
                float* urow = ulist + ((size_t)(b * CAP_U + slot)) * 32 + (tid & 7) * 4;
                f4v o; o.x = vv[0]; o.y = vv[1]; o.z = vv[2]; o.w = vv[3];
                *(f4v*)urow = o;
                if ((tid & 7) == 0) ws[WS_NLIST + b * CAP_U + slot] = (uint32_t)n;
            }
        }
    }
    // reduce above-counts across the 8 lanes sharing each feature group (stride-8 classes)
#pragma unroll
    for (int j = 0; j < 4; ++j) {
        uint32_t a = acnt[j];
        a += __shfl_down(a, 32);
        a += __shfl_down(a, 16);
        a += __shfl_down(a, 8);
        acnt[j] = a;
    }
    if ((tid & 63) < 8) {
#pragma unroll
        for (int j = 0; j < 4; ++j) atomicAdd(&labove[fb + j], acnt[j]);
    }
    // block min via wave shfl + 4-slot LDS
    mreg = min(mreg, (uint32_t)__shfl_down(mreg, 32));
    mreg = min(mreg, (uint32_t)__shfl_down(mreg, 16));
    mreg = min(mreg, (uint32_t)__shfl_down(mreg, 8));
    mreg = min(mreg, (uint32_t)__shfl_down(mreg, 4));
    mreg = min(mreg, (uint32_t)__shfl_down(mreg, 2));
    mreg = min(mreg, (uint32_t)__shfl_down(mreg, 1));
    if (lane == 0) rmin[tid >> 6] = mreg;
    __syncthreads();
    if (tid == 0) {
        uint32_t m = min(min(rmin[0], rmin[1]), min(rmin[2], rmin[3]));
        atomicMin(&ws[WS_MIN], m);
    }
    if (tid < 32) {
        uint32_t c = lcnt[tid];
        ws[WS_PA + (size_t)(b * 128 + blk) * 32 + tid] = labove[tid];
        ws[WS_PI + (size_t)(b * 128 + blk) * 32 + tid] = c;
        uint32_t cc = c > CAP_LDS ? (uint32_t)CAP_LDS : c;
        lcnt[tid] = cc;
        lbase[tid] = atomicAdd(&ws[WS_EQC + b * 32 + tid], cc);
    }
    __syncthreads();
    {   // parallel flush: 32 features x 8 threads each (cached: kselect re-reads)
        const int f = tid >> 3;
        const int l8 = tid & 7;
        const uint32_t c = lcnt[f], base = lbase[f];
        const size_t cb = (size_t)(b * 32 + f) * CAP_COL;
        for (uint32_t i = l8; i < c; i += 8) {
            uint32_t pos = base + i;
            if (pos < CAP_COL) gcand[cb + pos] = lbuf[f][i];
        }
    }
}

// ---- 2) merged check + fallback + threshold: one block per column ----
__global__ __launch_bounds__(256) void kselect(const float* __restrict__ xf,
                                               const float* __restrict__ mask,
                                               uint32_t* __restrict__ ws) {
    __shared__ uint32_t lh[4096];
    __shared__ uint64_t buf[4096];
    __shared__ uint32_t cs[256];
    __shared__ uint32_t sh_bin, sh_rr, sh_cnt, okf;
    const int col = blockIdx.x;
    const int b = col >> 5;
    const int f = col & 31;
    const int tid = threadIdx.x;

    // --- phase 0: verify band per column: A < K <= A+I ; else per-column hist fallback ---
    {
        uint32_t a = 0, i = 0;
        if (tid < 128) {
            a = ws[WS_PA + (size_t)(b * 128 + tid) * 32 + f];
            i = ws[WS_PI + (size_t)(b * 128 + tid) * 32 + f];
        }
        cs[tid] = a; lh[tid] = i;
        __syncthreads();
        for (int off = 64; off >= 1; off >>= 1) {
            if (tid < off) { cs[tid] += cs[tid + off]; lh[tid] += lh[tid + off]; }
            __syncthreads();
        }
        if (tid == 0) {
            uint32_t A = cs[0], I = lh[0];
            ws[WS_PREF + col] = GBIN;
            if (A < (uint32_t)KSEL && (uint32_t)KSEL <= A + I) {
                ws[WS_REM + col] = (uint32_t)KSEL - A;
                okf = 1u;
            } else {
                ws[WS_FLAG + b] = 1u;
                okf = 0u;
            }
        }
        __syncthreads();
    }
    if (!okf) {   // fallback: exact per-column 9-bit hist + recollect (rare)
        __shared__ uint32_t sp, sr;
        for (int i = tid; i < 512; i += 256) lh[i] = 0;
        __syncthreads();
        const float* xc = xf + (size_t)b * NN * FF + f;
        for (int n = tid; n < NN; n += 256)
            atomicAdd(&lh[fkey(xc[(size_t)n * FF]) >> 23], 1u);
        __syncthreads();
        uint32_t b0 = lh[2 * tid], b1 = lh[2 * tid + 1];
        cs[tid] = b0 + b1;
        __syncthreads();
        for (int off = 1; off < 256; off <<= 1) {
            uint32_t t = (tid + off < 256) ? cs[tid + off] : 0;
            __syncthreads();
            cs[tid] += t;
            __syncthreads();
        }
        {
            uint32_t E = (tid < 255) ? cs[tid + 1] : 0;
            uint32_t S1 = b1 + E;
            uint32_t S0 = b0 + S1;
            if (S0 >= (uint32_t)KSEL && S1 < (uint32_t)KSEL) { sp = 2 * tid;     sr = (uint32_t)KSEL - S1; }
            if (S1 >= (uint32_t)KSEL && E  < (uint32_t)KSEL) { sp = 2 * tid + 1; sr = (uint32_t)KSEL - E; }
        }
        __syncthreads();
        const uint32_t p = sp;
        if (tid == 0) {
            ws[WS_PREF + col] = p;
            ws[WS_REM + col] = sr;
            ws[WS_EQC + col] = 0u;
        }
        __syncthreads();
        uint64_t* gcand = (uint64_t*)(ws + WS_CAND);
        for (int n = tid; n < NN; n += 256) {
            uint32_t key = fkey(xc[(size_t)n * FF]);
            if ((key >> 23) == p) {
                uint32_t pos = atomicAdd(&ws[WS_EQC + col], 1u);
                if (pos < CAP_COL)
                    gcand[(size_t)col * CAP_COL + pos] = ((uint64_t)key << 32) | (uint32_t)n;
            }
        }
        __syncthreads();
    }

    // --- phase 1: exact threshold: decode (xkey,n)->skey; radix-select r-th largest ---
    uint32_t cnt = ws[WS_EQC + col];
    if (cnt > CAP_COL) cnt = CAP_COL;
    uint32_t rr = ws[WS_REM + col];
    if (rr > cnt) rr = cnt;
    if (rr == 0) rr = 1;
    const uint64_t* cand = (const uint64_t*)(ws + WS_CAND) + (size_t)col * CAP_COL;
    const float mn = __uint_as_float(ws[WS_MIN]);
    const bool m1 = ws[WS_MNOT] == 0u;
    const float* mb = mask + (size_t)b * NN;

    auto mkv = [&](uint64_t c) -> uint64_t {
        uint32_t xk = (uint32_t)(c >> 32);
        uint32_t n  = (uint32_t)c;
        uint32_t xb = (xk & 0x80000000u) ? (xk & 0x7FFFFFFFu) : ~xk;
        float mk = m1 ? 1.0f : mb[n];
        float sv = ((__uint_as_float(xb) + mn) + EPSF) * mk;
        return ((uint64_t)fkey(sv) << 32) | (uint32_t)(~n);
    };

    for (int i = tid; i < 4096; i += 256) lh[i] = 0;
    __syncthreads();
    for (uint32_t i = tid; i < cnt; i += 256)
        atomicAdd(&lh[(uint32_t)(mkv(cand[i]) >> 52)], 1u);
    __syncthreads();
    const int c0 = tid * 16;
    {
        uint32_t run = 0;
        for (int i = 15; i >= 0; --i) { run += lh[c0 + i]; lh[c0 + i] = run; }
        cs[tid] = run;
    }
    __syncthreads();
    for (int off = 1; off < 256; off <<= 1) {
        uint32_t t = (tid + off < 256) ? cs[tid + off] : 0;
        __syncthreads();
        cs[tid] += t;
        __syncthreads();
    }
    {
        uint32_t E = (tid < 255) ? cs[tid + 1] : 0;
        for (int i = 0; i < 16; ++i) {
            uint32_t S  = lh[c0 + i] + E;
            uint32_t Sn = ((i < 15) ? lh[c0 + i + 1] : 0u) + E;
            if (S >= rr && Sn < rr) { sh_bin = (uint32_t)(c0 + i); sh_rr = rr - Sn; }
        }
    }
    __syncthreads();
    uint64_t prefix = sh_bin;
    rr = sh_rr;
    int shift = 52;
    __syncthreads();

    uint32_t lcnt;
    while (true) {
        if (tid == 0) sh_cnt = 0;
        __syncthreads();
        for (uint32_t i = tid; i < cnt; i += 256) {
            uint64_t v = mkv(cand[i]);
            if ((v >> shift) == prefix) {
                uint32_t idx = atomicAdd(&sh_cnt, 1u);
                if (idx < 4096u) buf[idx] = v;
            }
        }
        __syncthreads();
        if (sh_cnt <= 4096u) { lcnt = sh_cnt; break; }
        if (tid < 256) lh[tid] = 0;
        __syncthreads();
        for (uint32_t i = tid; i < cnt; i += 256) {
            uint64_t v = mkv(cand[i]);
            if ((v >> shift) == prefix)
                atomicAdd(&lh[(uint32_t)(v >> (shift - 8)) & 255u], 1u);
        }
        __syncthreads();
        for (int off = 1; off < 256; off <<= 1) {
            uint32_t t = (tid + off < 256) ? lh[tid + off] : 0;
            __syncthreads();
            lh[tid] += t;
            __syncthreads();
        }
        {
            uint32_t Sb = lh[tid];
            uint32_t Sb1 = (tid < 255) ? lh[tid + 1] : 0;
            if (Sb >= rr && Sb1 < rr) { sh_bin = (uint32_t)tid; sh_rr = rr - Sb1; }
        }
        __syncthreads();
        prefix = (prefix << 8) | sh_bin;
        rr = sh_rr;
        shift -= 8;
        __syncthreads();
    }

    while (shift > 0) {
        const int w = (shift >= 8) ? 8 : shift;
        lh[tid] = 0;
        __syncthreads();
        for (uint32_t i = tid; i < lcnt; i += 256) {
            uint64_t v = buf[i];
            if ((v >> shift) == prefix)
                atomicAdd(&lh[(uint32_t)(v >> (shift - w)) & ((1u << w) - 1u)], 1u);
        }
        __syncthreads();
        for (int off = 1; off < 256; off <<= 1) {
            uint32_t t = (tid + off < 256) ? lh[tid + off] : 0;
            __syncthreads();
            lh[tid] += t;
            __syncthreads();
        }
        {
            uint32_t Sb = lh[tid];
            uint32_t Sb1 = (tid < 255) ? lh[tid + 1] : 0;
            if (Sb >= rr && Sb1 < rr) { sh_bin = (uint32_t)tid; sh_rr = rr - Sb1; }
        }
        __syncthreads();
        prefix = (prefix << w) | sh_bin;
        rr = sh_rr;
        shift -= w;
        __syncthreads();
    }
    if (tid == 0) ((uint64_t*)(ws + WS_T))[col] = prefix;
}

// ---- 3) full remark fallback: no-op unless batch flagged or CAP_U overflowed ----
__global__ __launch_bounds__(256) void kmark_full(const float* __restrict__ xf, const float* __restrict__ mask,
                                                  uint32_t* __restrict__ ws, float* __restrict__ upd,
                                                  float* __restrict__ omask) {
    const int b = blockIdx.x >> 7;
    if (!(ws[WS_FLAG + b] || ws[WS_UCNT + b] > CAP_U)) return;
    __shared__ uint32_t lp[32];
    __shared__ uint64_t lT[32];
    __shared__ float lmin;
    const int blk = blockIdx.x & 127;
    const int tid = threadIdx.x;
    if (tid < 32) {
        lp[tid] = ws[WS_PREF + b * 32 + tid];
        lT[tid] = ((const uint64_t*)(ws + WS_T))[b * 32 + tid];
    }
    if (tid == 0) lmin = __uint_as_float(ws[WS_MIN]);
    __syncthreads();
    const float4* x4 = (const float4*)xf + (size_t)b * 524288;
    f4v* o4 = (f4v*)omask + (size_t)b * 524288;
    const float mn = lmin;
    const int lane = tid & 63;
#pragma unroll
    for (int c = 0; c < 2; ++c) {
        float4 v[8];
#pragma unroll
        for (int k = 0; k < 8; ++k) v[k] = x4[blk * 4096 + c * 2048 + k * 256 + tid];
#pragma unroll
        for (int k = 0; k < 8; ++k) {
            const int e = blk * 4096 + c * 2048 + k * 256 + tid;
            const int n = e >> 3;
            const int fb = (e & 7) * 4;
            float vv[4] = {v[k].x, v[k].y, v[k].z, v[k].w};
            bool sel = false;
#pragma unroll
            for (int j = 0; j < 4; ++j) {
                uint32_t key = fkey(vv[j]);
                uint32_t k9 = key >> 23;
                uint32_t p = lp[fb + j];
                if (k9 > p) sel = true;
                else if (k9 == p) {
                    float mk = mask[(size_t)b * NN + n];
                    float sv = ((vv[j] + mn) + EPSF) * mk;
                    uint64_t kk = ((uint64_t)fkey(sv) << 32) | (uint32_t)(~(uint32_t)n);
                    if (kk >= lT[fb + j]) sel = true;
                }
            }
            unsigned long long bal = __ballot(sel);
            uint32_t grp = (uint32_t)(bal >> (lane & 56)) & 0xFFu;
            float u1 = grp ? 1.0f : 0.0f;
            f4v o;
            o.x = vv[0] * u1; o.y = vv[1] * u1; o.z = vv[2] * u1; o.w = vv[3] * u1;
            o4[e] = o;
            if ((tid & 7) == 0) upd[(size_t)b * NN + n] = u1;
        }
    }
}

// ---- 4) finish unsure rows exactly (band logic; bucket logic if batch flagged) ----
__global__ __launch_bounds__(256) void kfix2(const float* __restrict__ mask, uint32_t* __restrict__ ws,
                                             float* __restrict__ upd, float* __restrict__ omask) {
    __shared__ uint32_t lp[32];
    __shared__ uint64_t lT[32];
    __shared__ float lmin;
    const int b = blockIdx.x;
    const int tid = threadIdx.x;
    if (tid < 32) {
        lp[tid] = ws[WS_PREF + b * 32 + tid];
        lT[tid] = ((const uint64_t*)(ws + WS_T))[b * 32 + tid];
    }
    if (tid == 0) lmin = __uint_as_float(ws[WS_MIN]);
    __syncthreads();
    const bool flagged = ws[WS_FLAG + b] != 0u;
    uint32_t cnt = ws[WS_UCNT + b];
    if (cnt > CAP_U) cnt = CAP_U;
    const float mn = lmin;
    const int lane = tid & 63;
    const float* ulist = (const float*)(ws + WS_ULIST);
    f4v* o4 = (f4v*)omask + (size_t)b * 524288;
    for (uint32_t r0 = 0; r0 < cnt; r0 += 32) {
        uint32_t r = r0 + (tid >> 3);
        bool act = r < cnt;
        uint32_t n = 0;
        f4v vx = {0, 0, 0, 0};
        bool sel = false;
        if (act) {
            n = ws[WS_NLIST + b * CAP_U + r];
            vx = *(const f4v*)(ulist + ((size_t)(b * CAP_U + r)) * 32 + (tid & 7) * 4);
            float mk = mask[(size_t)b * NN + n];
            const int fb = (tid & 7) * 4;
            float vv[4] = {vx.x, vx.y, vx.z, vx.w};
#pragma unroll
            for (int j = 0; j < 4; ++j) {
                uint32_t key = fkey(vv[j]);
                if (!flagged) {
                    if (key >= KEYHI) sel = true;
                    else if (key >= KEYLO) {
                        float sv = ((vv[j] + mn) + EPSF) * mk;
                        uint64_t kk = ((uint64_t)fkey(sv) << 32) | (uint32_t)(~(uint32_t)n);
                        if (kk >= lT[fb + j]) sel = true;
                    }
                } else {
                    uint32_t k9 = key >> 23;
                    uint32_t p = lp[fb + j];
                    if (k9 > p) sel = true;
                    else if (k9 == p) {
                        float sv = ((vv[j] + mn) + EPSF) * mk;
                        uint64_t kk = ((uint64_t)fkey(sv) << 32) | (uint32_t)(~(uint32_t)n);
                        if (kk >= lT[fb + j]) sel = true;
                    }
                }
            }
        }
        unsigned long long bal = __ballot(sel);
        uint32_t grp = (uint32_t)(bal >> (lane & 56)) & 0xFFu;
        if (act) {
            float u1 = grp ? 1.0f : 0.0f;
            f4v o;
            o.x = vx.x * u1; o.y = vx.y * u1; o.z = vx.z * u1; o.w = vx.w * u1;
            o4[(size_t)n * 8 + (tid & 7)] = o;
            if ((tid & 7) == 0) upd[(size_t)b * NN + n] = u1;
        }
    }
}

extern "C" void kernel_launch(void* const* d_in, const int* in_sizes, int n_in,
                              void* d_out, int out_size, void* d_ws, size_t ws_size,
                              hipStream_t stream) {
    const float* x = (const float*)d_in[0];
    const float* mask = (const float*)d_in[1];
    float* upd = (float*)d_out;                       // (B,N,1)
    float* omask = (float*)d_out + (size_t)BB * NN;   // (B,N,F)
    uint32_t* ws = (uint32_t*)d_ws;

    hipMemsetAsync((char*)d_ws + (size_t)WS_MIN * 4, 0xFF, 4, stream);
    hipMemsetAsync((char*)d_ws + (size_t)WS_EQC * 4, 0, 1080 * 4, stream);  // EQC+UCNT+FLAG+MNOT+PREF

    kfused<<<BB * BLKB, 256, 0, stream>>>(x, mask, ws, upd, omask);
    kselect<<<512, 256, 0, stream>>>(x, mask, ws);    // check + fallback + threshold
    kmark_full<<<BB * 128, 256, 0, stream>>>(x, mask, ws, upd, omask);
    kfix2<<<BB, 256, 0, stream>>>(mask, ws, upd, omask);
}

// Round 21
// 86.196 us; speedup vs baseline: 1.0903x; 1.0903x over previous
//
#include <hip/hip_runtime.h>
#include <stdint.h>

#define BB   16
#define NN   65536
#define FF   32
#define KSEL 16384
#define EPSF 1e-10f
#define GBIN 382u                // fallback 9-bit bucket logic (flagged path)
#define CAP_COL 11264            // candidates per column (fallback needs ~9.8K)
#define CAP_LDS 64               // LDS staged candidates per feature per block (λ≈22.5)
#define BLKB 128                 // kfused blocks per batch
#define CAP_U   2048             // unsure rows per batch (expected ~10)

typedef float f4v __attribute__((ext_vector_type(4)));

__device__ __forceinline__ uint32_t fkey(float s) {
    uint32_t u = __float_as_uint(s);
    return (u & 0x80000000u) ? ~u : (u | 0x80000000u);
}
// band bounds: float domain [0.64, 0.71) — equivalent to key domain (monotone)
#define BANDLO 0.64f
#define BANDHI 0.71f
#define KEYLO fkey(0.64f)
#define KEYHI fkey(0.71f)

// ---- workspace layout (uint32 element offsets), ~51 MB ----
#define WS_MIN    0                          // 1 word (memset 0xFF)
#define WS_REM    8                          // [512]
#define WS_T      1032                       // u64[512] (byte 4128, 8-aligned)
#define WS_EQC    2056                       // [512] cand counters   (memset 0 from here...)
#define WS_UCNT   2568                       // [16] unsure counters
#define WS_FLAG   2584                       // [16] guess-miss flags
#define WS_MNOT   2600                       // 1 word: nonzero if mask has a non-1.0 element
#define WS_PREF   2624                       // [512] bucket per column (...to here: 1080 words)
#define WS_PA     4096                       // [2048][32] per-block above-counts
#define WS_PI     69632                      // [2048][32] per-block in-counts
#define WS_NLIST  135168                     // [16][CAP_U] row indices
#define WS_ULIST  167936                     // [16][CAP_U][32] f32 rows
#define WS_CAND   1216512                    // u64[512][CAP_COL] (byte 4866048, 8-aligned)

// ---- 1) fused: min + mask-check + band counts (register) + cand collect + output mark ----
__global__ __launch_bounds__(256, 4) void kfused(const float* __restrict__ xf,
                                                 const float* __restrict__ mask,
                                                 uint32_t* __restrict__ ws,
                                                 float* __restrict__ upd,
                                                 float* __restrict__ omask) {
    __shared__ uint64_t lbuf[32][CAP_LDS];
    __shared__ uint32_t lcnt[32], lbase[32], labove[32];
    __shared__ uint32_t rmin[4];
    const int b = blockIdx.x >> 7;
    const int blk = blockIdx.x & 127;
    const int tid = threadIdx.x;
    if (tid < 32) { lcnt[tid] = 0; labove[tid] = 0; }
    __syncthreads();
    if (tid < 128) {  // mask uniformity check: 128 float4 slice per block covers all of mask
        float4 a = ((const float4*)mask)[(size_t)blockIdx.x * 128 + tid];
        if ((a.x != 1.0f) | (a.y != 1.0f) | (a.z != 1.0f) | (a.w != 1.0f)) ws[WS_MNOT] = 1u;
    }
    const float4* x4 = (const float4*)xf + (size_t)b * 524288;
    f4v* o4 = (f4v*)omask + (size_t)b * 524288;
    const int lane = tid & 63;
    const int fb = (tid & 7) * 4;            // this thread ALWAYS serves features fb..fb+3
    uint64_t* gcand = (uint64_t*)(ws + WS_CAND);
    float* ulist = (float*)(ws + WS_ULIST);
    uint32_t mreg = 0xFFFFFFFFu;
    uint32_t acnt[4] = {0, 0, 0, 0};
    float4 v[16];
#pragma unroll
    for (int k = 0; k < 16; ++k) v[k] = x4[blk * 4096 + k * 256 + tid];
    __builtin_amdgcn_sched_barrier(0);
#pragma unroll
    for (int k = 0; k < 16; ++k) {
        const int e = blk * 4096 + k * 256 + tid;
        const int n = e >> 3;
        float vv[4] = {v[k].x, v[k].y, v[k].z, v[k].w};
        bool ab[4], ib[4];
#pragma unroll
        for (int j = 0; j < 4; ++j) {
            uint32_t u = __float_as_uint(vv[j]);
            uint32_t a = u & 0x7FFFFFFFu;
            mreg = a < mreg ? a : mreg;
            ab[j] = vv[j] >= BANDHI;
            ib[j] = (vv[j] >= BANDLO) & !ab[j];
            acnt[j] += ab[j] ? 1u : 0u;
            if (ib[j]) {                       // rare (2.2%): compute key only here
                const int f = fb + j;
                uint64_t v64 = ((uint64_t)fkey(vv[j]) << 32) | (uint32_t)n;
                uint32_t idx = atomicAdd(&lcnt[f], 1u);
                if (idx < CAP_LDS) {
                    lbuf[f][idx] = v64;
                } else {               // statistically never (22.5 avg vs 64 cap)
                    uint32_t col = (uint32_t)(b * 32 + f);
                    uint32_t pos = atomicAdd(&ws[WS_EQC + col], 1u);
                    if (pos < CAP_COL) gcand[(size_t)col * CAP_COL + pos] = v64;
                }
            }
        }
        bool sure = ab[0] | ab[1] | ab[2] | ab[3];
        bool bnd = ib[0] | ib[1] | ib[2] | ib[3];
        unsigned long long balS = __ballot(sure);
        unsigned long long balB = __ballot(bnd);
        uint32_t grpS = (uint32_t)(balS >> (lane & 56)) & 0xFFu;
        uint32_t grpB = (uint32_t)(balB >> (lane & 56)) & 0xFFu;
        if (grpS || !grpB) {                       // decided row (sure OR out): branchless store
            float u1 = grpS ? 1.0f : 0.0f;
            f4v o;
            o.x = vv[0] * u1; o.y = vv[1] * u1; o.z = vv[2] * u1; o.w = vv[3] * u1;
            __builtin_nontemporal_store(o, &o4[e]);
            if ((tid & 7) == 0) upd[(size_t)b * NN + n] = u1;   // cached: 4MB, L2 assembles lines
        } else {                                   // unsure: defer to kfix2 (~1e-4 of rows)
            uint32_t slot = 0xFFFFFFFFu;
            if ((tid & 7) == 0) slot = atomicAdd(&ws[WS_UCNT + b], 1u);
            slot = __shfl(slot, (lane & 56));
            if (slot < CAP_U) {
                float* urow = ulist + ((size_t)(b * CAP_U + slot)) * 32 + (tid & 7) * 4;
                f4v o; o.x = vv[0]; o.y = vv[1]; o.z = vv[2]; o.w = vv[3];
                *(f4v*)urow = o;
                if ((tid & 7) == 0) ws[WS_NLIST + b * CAP_U + slot] = (uint32_t)n;
            }
        }
    }
    // reduce above-counts across the 8 lanes sharing each feature group (stride-8 classes)
#pragma unroll
    for (int j = 0; j < 4; ++j) {
        uint32_t a = acnt[j];
        a += __shfl_down(a, 32);
        a += __shfl_down(a, 16);
        a += __shfl_down(a, 8);
        acnt[j] = a;
    }
    if ((tid & 63) < 8) {
#pragma unroll
        for (int j = 0; j < 4; ++j) atomicAdd(&labove[fb + j], acnt[j]);
    }
    // block min via wave shfl + 4-slot LDS
    mreg = min(mreg, (uint32_t)__shfl_down(mreg, 32));
    mreg = min(mreg, (uint32_t)__shfl_down(mreg, 16));
    mreg = min(mreg, (uint32_t)__shfl_down(mreg, 8));
    mreg = min(mreg, (uint32_t)__shfl_down(mreg, 4));
    mreg = min(mreg, (uint32_t)__shfl_down(mreg, 2));
    mreg = min(mreg, (uint32_t)__shfl_down(mreg, 1));
    if (lane == 0) rmin[tid >> 6] = mreg;
    __syncthreads();
    if (tid == 0) {
        uint32_t m = min(min(rmin[0], rmin[1]), min(rmin[2], rmin[3]));
        atomicMin(&ws[WS_MIN], m);
    }
    if (tid < 32) {
        uint32_t c = lcnt[tid];
        ws[WS_PA + (size_t)(b * 128 + blk) * 32 + tid] = labove[tid];
        ws[WS_PI + (size_t)(b * 128 + blk) * 32 + tid] = c;
        uint32_t cc = c > CAP_LDS ? (uint32_t)CAP_LDS : c;
        lcnt[tid] = cc;
        lbase[tid] = atomicAdd(&ws[WS_EQC + b * 32 + tid], cc);
    }
    __syncthreads();
    {   // parallel flush: 32 features x 8 threads each (cached: kselect re-reads)
        const int f = tid >> 3;
        const int l8 = tid & 7;
        const uint32_t c = lcnt[f], base = lbase[f];
        const size_t cb = (size_t)(b * 32 + f) * CAP_COL;
        for (uint32_t i = l8; i < c; i += 8) {
            uint32_t pos = base + i;
            if (pos < CAP_COL) gcand[cb + pos] = lbuf[f][i];
        }
    }
}

// ---- 2) merged check + fallback + threshold: one block per column ----
__global__ __launch_bounds__(256) void kselect(const float* __restrict__ xf,
                                               const float* __restrict__ mask,
                                               uint32_t* __restrict__ ws) {
    __shared__ uint32_t lh[4096];
    __shared__ uint64_t buf[4096];
    __shared__ uint32_t cs[256];
    __shared__ uint32_t sh_bin, sh_rr, sh_cnt, okf;
    const int col = blockIdx.x;
    const int b = col >> 5;
    const int f = col & 31;
    const int tid = threadIdx.x;

    // --- phase 0: verify band per column: A < K <= A+I ; else per-column hist fallback ---
    {
        uint32_t a = 0, i = 0;
        if (tid < 128) {
            a = ws[WS_PA + (size_t)(b * 128 + tid) * 32 + f];
            i = ws[WS_PI + (size_t)(b * 128 + tid) * 32 + f];
        }
        cs[tid] = a; lh[tid] = i;
        __syncthreads();
        for (int off = 64; off >= 1; off >>= 1) {
            if (tid < off) { cs[tid] += cs[tid + off]; lh[tid] += lh[tid + off]; }
            __syncthreads();
        }
        if (tid == 0) {
            uint32_t A = cs[0], I = lh[0];
            ws[WS_PREF + col] = GBIN;
            if (A < (uint32_t)KSEL && (uint32_t)KSEL <= A + I) {
                ws[WS_REM + col] = (uint32_t)KSEL - A;
                okf = 1u;
            } else {
                ws[WS_FLAG + b] = 1u;
                okf = 0u;
            }
        }
        __syncthreads();
    }
    if (!okf) {   // fallback: exact per-column 9-bit hist + recollect (rare)
        __shared__ uint32_t sp, sr;
        for (int i = tid; i < 512; i += 256) lh[i] = 0;
        __syncthreads();
        const float* xc = xf + (size_t)b * NN * FF + f;
        for (int n = tid; n < NN; n += 256)
            atomicAdd(&lh[fkey(xc[(size_t)n * FF]) >> 23], 1u);
        __syncthreads();
        uint32_t b0 = lh[2 * tid], b1 = lh[2 * tid + 1];
        cs[tid] = b0 + b1;
        __syncthreads();
        for (int off = 1; off < 256; off <<= 1) {
            uint32_t t = (tid + off < 256) ? cs[tid + off] : 0;
            __syncthreads();
            cs[tid] += t;
            __syncthreads();
        }
        {
            uint32_t E = (tid < 255) ? cs[tid + 1] : 0;
            uint32_t S1 = b1 + E;
            uint32_t S0 = b0 + S1;
            if (S0 >= (uint32_t)KSEL && S1 < (uint32_t)KSEL) { sp = 2 * tid;     sr = (uint32_t)KSEL - S1; }
            if (S1 >= (uint32_t)KSEL && E  < (uint32_t)KSEL) { sp = 2 * tid + 1; sr = (uint32_t)KSEL - E; }
        }
        __syncthreads();
        const uint32_t p = sp;
        if (tid == 0) {
            ws[WS_PREF + col] = p;
            ws[WS_REM + col] = sr;
            ws[WS_EQC + col] = 0u;
        }
        __syncthreads();
        uint64_t* gcand = (uint64_t*)(ws + WS_CAND);
        for (int n = tid; n < NN; n += 256) {
            uint32_t key = fkey(xc[(size_t)n * FF]);
            if ((key >> 23) == p) {
                uint32_t pos = atomicAdd(&ws[WS_EQC + col], 1u);
                if (pos < CAP_COL)
                    gcand[(size_t)col * CAP_COL + pos] = ((uint64_t)key << 32) | (uint32_t)n;
            }
        }
        __syncthreads();
    }

    // --- phase 1: exact threshold: decode (xkey,n)->skey; radix-select r-th largest ---
    uint32_t cnt = ws[WS_EQC + col];
    if (cnt > CAP_COL) cnt = CAP_COL;
    uint32_t rr = ws[WS_REM + col];
    if (rr > cnt) rr = cnt;
    if (rr == 0) rr = 1;
    const uint64_t* cand = (const uint64_t*)(ws + WS_CAND) + (size_t)col * CAP_COL;
    const float mn = __uint_as_float(ws[WS_MIN]);
    const bool m1 = ws[WS_MNOT] == 0u;
    const float* mb = mask + (size_t)b * NN;

    auto mkv = [&](uint64_t c) -> uint64_t {
        uint32_t xk = (uint32_t)(c >> 32);
        uint32_t n  = (uint32_t)c;
        uint32_t xb = (xk & 0x80000000u) ? (xk & 0x7FFFFFFFu) : ~xk;
        float mk = m1 ? 1.0f : mb[n];
        float sv = ((__uint_as_float(xb) + mn) + EPSF) * mk;
        return ((uint64_t)fkey(sv) << 32) | (uint32_t)(~n);
    };

    for (int i = tid; i < 4096; i += 256) lh[i] = 0;
    __syncthreads();
    for (uint32_t i = tid; i < cnt; i += 256)
        atomicAdd(&lh[(uint32_t)(mkv(cand[i]) >> 52)], 1u);
    __syncthreads();
    const int c0 = tid * 16;
    {
        uint32_t run = 0;
        for (int i = 15; i >= 0; --i) { run += lh[c0 + i]; lh[c0 + i] = run; }
        cs[tid] = run;
    }
    __syncthreads();
    for (int off = 1; off < 256; off <<= 1) {
        uint32_t t = (tid + off < 256) ? cs[tid + off] : 0;
        __syncthreads();
        cs[tid] += t;
        __syncthreads();
    }
    {
        uint32_t E = (tid < 255) ? cs[tid + 1] : 0;
        for (int i = 0; i < 16; ++i) {
            uint32_t S  = lh[c0 + i] + E;
            uint32_t Sn = ((i < 15) ? lh[c0 + i + 1] : 0u) + E;
            if (S >= rr && Sn < rr) { sh_bin = (uint32_t)(c0 + i); sh_rr = rr - Sn; }
        }
    }
    __syncthreads();
    uint64_t prefix = sh_bin;
    rr = sh_rr;
    int shift = 52;
    __syncthreads();

    uint32_t lcnt;
    while (true) {
        if (tid == 0) sh_cnt = 0;
        __syncthreads();
        for (uint32_t i = tid; i < cnt; i += 256) {
            uint64_t v = mkv(cand[i]);
            if ((v >> shift) == prefix) {
                uint32_t idx = atomicAdd(&sh_cnt, 1u);
                if (idx < 4096u) buf[idx] = v;
            }
        }
        __syncthreads();
        if (sh_cnt <= 4096u) { lcnt = sh_cnt; break; }
        if (tid < 256) lh[tid] = 0;
        __syncthreads();
        for (uint32_t i = tid; i < cnt; i += 256) {
            uint64_t v = mkv(cand[i]);
            if ((v >> shift) == prefix)
                atomicAdd(&lh[(uint32_t)(v >> (shift - 8)) & 255u], 1u);
        }
        __syncthreads();
        for (int off = 1; off < 256; off <<= 1) {
            uint32_t t = (tid + off < 256) ? lh[tid + off] : 0;
            __syncthreads();
            lh[tid] += t;
            __syncthreads();
        }
        {
            uint32_t Sb = lh[tid];
            uint32_t Sb1 = (tid < 255) ? lh[tid + 1] : 0;
            if (Sb >= rr && Sb1 < rr) { sh_bin = (uint32_t)tid; sh_rr = rr - Sb1; }
        }
        __syncthreads();
        prefix = (prefix << 8) | sh_bin;
        rr = sh_rr;
        shift -= 8;
        __syncthreads();
    }

    while (shift > 0) {
        const int w = (shift >= 8) ? 8 : shift;
        lh[tid] = 0;
        __syncthreads();
        for (uint32_t i = tid; i < lcnt; i += 256) {
            uint64_t v = buf[i];
            if ((v >> shift) == prefix)
                atomicAdd(&lh[(uint32_t)(v >> (shift - w)) & ((1u << w) - 1u)], 1u);
        }
        __syncthreads();
        for (int off = 1; off < 256; off <<= 1) {
            uint32_t t = (tid + off < 256) ? lh[tid + off] : 0;
            __syncthreads();
            lh[tid] += t;
            __syncthreads();
        }
        {
            uint32_t Sb = lh[tid];
            uint32_t Sb1 = (tid < 255) ? lh[tid + 1] : 0;
            if (Sb >= rr && Sb1 < rr) { sh_bin = (uint32_t)tid; sh_rr = rr - Sb1; }
        }
        __syncthreads();
        prefix = (prefix << w) | sh_bin;
        rr = sh_rr;
        shift -= w;
        __syncthreads();
    }
    if (tid == 0) ((uint64_t*)(ws + WS_T))[col] = prefix;
}

// ---- 3) full remark fallback: no-op unless batch flagged or CAP_U overflowed ----
__global__ __launch_bounds__(256) void kmark_full(const float* __restrict__ xf, const float* __restrict__ mask,
                                                  uint32_t* __restrict__ ws, float* __restrict__ upd,
                                                  float* __restrict__ omask) {
    const int b = blockIdx.x >> 7;
    if (!(ws[WS_FLAG + b] || ws[WS_UCNT + b] > CAP_U)) return;
    __shared__ uint32_t lp[32];
    __shared__ uint64_t lT[32];
    __shared__ float lmin;
    const int blk = blockIdx.x & 127;
    const int tid = threadIdx.x;
    if (tid < 32) {
        lp[tid] = ws[WS_PREF + b * 32 + tid];
        lT[tid] = ((const uint64_t*)(ws + WS_T))[b * 32 + tid];
    }
    if (tid == 0) lmin = __uint_as_float(ws[WS_MIN]);
    __syncthreads();
    const float4* x4 = (const float4*)xf + (size_t)b * 524288;
    f4v* o4 = (f4v*)omask + (size_t)b * 524288;
    const float mn = lmin;
    const int lane = tid & 63;
#pragma unroll
    for (int c = 0; c < 2; ++c) {
        float4 v[8];
#pragma unroll
        for (int k = 0; k < 8; ++k) v[k] = x4[blk * 4096 + c * 2048 + k * 256 + tid];
#pragma unroll
        for (int k = 0; k < 8; ++k) {
            const int e = blk * 4096 + c * 2048 + k * 256 + tid;
            const int n = e >> 3;
            const int fb = (e & 7) * 4;
            float vv[4] = {v[k].x, v[k].y, v[k].z, v[k].w};
            bool sel = false;
#pragma unroll
            for (int j = 0; j < 4; ++j) {
                uint32_t key = fkey(vv[j]);
                uint32_t k9 = key >> 23;
                uint32_t p = lp[fb + j];
                if (k9 > p) sel = true;
                else if (k9 == p) {
                    float mk = mask[(size_t)b * NN + n];
                    float sv = ((vv[j] + mn) + EPSF) * mk;
                    uint64_t kk = ((uint64_t)fkey(sv) << 32) | (uint32_t)(~(uint32_t)n);
                    if (kk >= lT[fb + j]) sel = true;
                }
            }
            unsigned long long bal = __ballot(sel);
            uint32_t grp = (uint32_t)(bal >> (lane & 56)) & 0xFFu;
            float u1 = grp ? 1.0f : 0.0f;
            f4v o;
            o.x = vv[0] * u1; o.y = vv[1] * u1; o.z = vv[2] * u1; o.w = vv[3] * u1;
            __builtin_nontemporal_store(o, &o4[e]);
            if ((tid & 7) == 0) upd[(size_t)b * NN + n] = u1;
        }
    }
}

// ---- 4) finish unsure rows exactly (band logic; bucket logic if batch flagged) ----
__global__ __launch_bounds__(256) void kfix2(const float* __restrict__ mask, uint32_t* __restrict__ ws,
                                             float* __restrict__ upd, float* __restrict__ omask) {
    __shared__ uint32_t lp[32];
    __shared__ uint64_t lT[32];
    __shared__ float lmin;
    const int b = blockIdx.x;
    const int tid = threadIdx.x;
    if (tid < 32) {
        lp[tid] = ws[WS_PREF + b * 32 + tid];
        lT[tid] = ((const uint64_t*)(ws + WS_T))[b * 32 + tid];
    }
    if (tid == 0) lmin = __uint_as_float(ws[WS_MIN]);
    __syncthreads();
    const bool flagged = ws[WS_FLAG + b] != 0u;
    uint32_t cnt = ws[WS_UCNT + b];
    if (cnt > CAP_U) cnt = CAP_U;
    const float mn = lmin;
    const int lane = tid & 63;
    const float* ulist = (const float*)(ws + WS_ULIST);
    f4v* o4 = (f4v*)omask + (size_t)b * 524288;
    for (uint32_t r0 = 0; r0 < cnt; r0 += 32) {
        uint32_t r = r0 + (tid >> 3);
        bool act = r < cnt;
        uint32_t n = 0;
        f4v vx = {0, 0, 0, 0};
        bool sel = false;
        if (act) {
            n = ws[WS_NLIST + b * CAP_U + r];
            vx = *(const f4v*)(ulist + ((size_t)(b * CAP_U + r)) * 32 + (tid & 7) * 4);
            float mk = mask[(size_t)b * NN + n];
            const int fb = (tid & 7) * 4;
            float vv[4] = {vx.x, vx.y, vx.z, vx.w};
#pragma unroll
            for (int j = 0; j < 4; ++j) {
                uint32_t key = fkey(vv[j]);
                if (!flagged) {
                    if (key >= KEYHI) sel = true;
                    else if (key >= KEYLO) {
                        float sv = ((vv[j] + mn) + EPSF) * mk;
                        uint64_t kk = ((uint64_t)fkey(sv) << 32) | (uint32_t)(~(uint32_t)n);
                        if (kk >= lT[fb + j]) sel = true;
                    }
                } else {
                    uint32_t k9 = key >> 23;
                    uint32_t p = lp[fb + j];
                    if (k9 > p) sel = true;
                    else if (k9 == p) {
                        float sv = ((vv[j] + mn) + EPSF) * mk;
                        uint64_t kk = ((uint64_t)fkey(sv) << 32) | (uint32_t)(~(uint32_t)n);
                        if (kk >= lT[fb + j]) sel = true;
                    }
                }
            }
        }
        unsigned long long bal = __ballot(sel);
        uint32_t grp = (uint32_t)(bal >> (lane & 56)) & 0xFFu;
        if (act) {
            float u1 = grp ? 1.0f : 0.0f;
            f4v o;
            o.x = vx.x * u1; o.y = vx.y * u1; o.z = vx.z * u1; o.w = vx.w * u1;
            o4[(size_t)n * 8 + (tid & 7)] = o;
            if ((tid & 7) == 0) upd[(size_t)b * NN + n] = u1;
        }
    }
}

extern "C" void kernel_launch(void* const* d_in, const int* in_sizes, int n_in,
                              void* d_out, int out_size, void* d_ws, size_t ws_size,
                              hipStream_t stream) {
    const float* x = (const float*)d_in[0];
    const float* mask = (const float*)d_in[1];
    float* upd = (float*)d_out;                       // (B,N,1)
    float* omask = (float*)d_out + (size_t)BB * NN;   // (B,N,F)
    uint32_t* ws = (uint32_t*)d_ws;

    hipMemsetAsync((char*)d_ws + (size_t)WS_MIN * 4, 0xFF, 4, stream);
    hipMemsetAsync((char*)d_ws + (size_t)WS_EQC * 4, 0, 1080 * 4, stream);  // EQC+UCNT+FLAG+MNOT+PREF

    kfused<<<BB * BLKB, 256, 0, stream>>>(x, mask, ws, upd, omask);
    kselect<<<512, 256, 0, stream>>>(x, mask, ws);    // check + fallback + threshold
    kmark_full<<<BB * 128, 256, 0, stream>>>(x, mask, ws, upd, omask);
    kfix2<<<BB, 256, 0, stream>>>(mask, ws, upd, omask);
}